// Round 1
// baseline (163.485 us; speedup 1.0000x reference)
//
#include <hip/hip_runtime.h>

#define BB 4096
#define TT 10
#define SS 301
#define HH 5
#define OO 3

#define L2E 1.442695040888963f   // log2(e)

__device__ __forceinline__ float rcp_hw(float x)  { return __builtin_amdgcn_rcpf(x); }
__device__ __forceinline__ float exp2_hw(float x) { return __builtin_amdgcn_exp2f(x); }

// Montgomery batch inversion: 5 reciprocals for the price of one v_rcp_f32
// plus 15 full-rate v_mul. d[i] > 0; product provably < 2^128 here.
__device__ __forceinline__ void inv5(const float d[HH], float inv[HH]) {
    float p1 = d[0] * d[1];
    float p2 = p1 * d[2];
    float p3 = p2 * d[3];
    float P  = p3 * d[4];
    float s3 = d[4] * d[3];
    float s2 = s3 * d[2];
    float s1 = s2 * d[1];
    float ip = rcp_hw(P);
    inv[0] = s1 * ip;
    inv[1] = (d[0] * s2) * ip;
    inv[2] = (p1 * s3) * ip;
    inv[3] = (p2 * d[4]) * ip;
    inv[4] = p3 * ip;
}

__global__ __launch_bounds__(256) void gru_kernel(
    const float* __restrict__ x,
    const float* __restrict__ w_ih,
    const float* __restrict__ w_hh,
    const float* __restrict__ b_ih,
    const float* __restrict__ b_hh,
    const float* __restrict__ fc_w,
    const float* __restrict__ fc_b,
    float* __restrict__ out)
{
    const int n = blockIdx.x * blockDim.x + threadIdx.x;
    const int b = n / SS;
    const int s = n - b * SS;
    if (b >= BB) return;

    // Wave-uniform weights: compiler emits scalar loads into SGPRs.
    float wih[3 * HH];
    float whh[3 * HH][HH];
    float brz[2 * HH];   // merged b_ih + b_hh for r,z gates
    float bin[HH];       // b_ih for n gate (outside r*)
    float bhn[HH];       // b_hh for n gate (inside r*)

    #pragma unroll
    for (int g = 0; g < 2 * HH; ++g) brz[g] = b_ih[g] + b_hh[g];
    #pragma unroll
    for (int j = 0; j < HH; ++j) {
        bin[j] = b_ih[2 * HH + j];
        bhn[j] = b_hh[2 * HH + j];
    }
    #pragma unroll
    for (int g = 0; g < 3 * HH; ++g) {
        wih[g] = w_ih[g];   // I == 1
        #pragma unroll
        for (int k = 0; k < HH; ++k) whh[g][k] = w_hh[g * HH + k];
    }

    // Preload all 10 inputs for this sample (coalesced across the wave per t).
    float xt[TT];
    const float* xp = x + (size_t)b * (TT * SS) + s;
    #pragma unroll
    for (int t = 0; t < TT; ++t) xt[t] = xp[t * SS];

    float h[HH];
    #pragma unroll
    for (int j = 0; j < HH; ++j) h[j] = 0.0f;

    #pragma unroll
    for (int t = 0; t < TT; ++t) {
        float ar[HH], az[HH], ain[HH], ahn[HH];
        #pragma unroll
        for (int j = 0; j < HH; ++j) {
            ar[j]  = __fmaf_rn(xt[t], wih[j],          brz[j]);
            az[j]  = __fmaf_rn(xt[t], wih[HH + j],     brz[HH + j]);
            ain[j] = __fmaf_rn(xt[t], wih[2 * HH + j], bin[j]);
            ahn[j] = bhn[j];
            #pragma unroll
            for (int k = 0; k < HH; ++k) {
                ar[j]  = __fmaf_rn(whh[j][k],          h[k], ar[j]);
                az[j]  = __fmaf_rn(whh[HH + j][k],     h[k], az[j]);
                ahn[j] = __fmaf_rn(whh[2 * HH + j][k], h[k], ahn[j]);
            }
        }

        // Sigmoid denominators for r and z gates: d = 1 + 2^(-log2e * a).
        // Saturation is graceful: exp2 -> 0 or big-but-finite; no inf in products.
        float dr[HH], dz[HH];
        #pragma unroll
        for (int j = 0; j < HH; ++j) {
            dr[j] = exp2_hw(-L2E * ar[j]) + 1.0f;
            dz[j] = exp2_hw(-L2E * az[j]) + 1.0f;
        }
        float r[HH], z[HH];
        inv5(dr, r);   // r[j] = sigmoid(ar[j])
        inv5(dz, z);   // z[j] = sigmoid(az[j])

        // tanh(y) = 1 - 2/(e^{2y}+1); clamp exponent (doubled scale) so the
        // 5-way product cannot overflow even pathologically.
        float dn[HH];
        #pragma unroll
        for (int j = 0; j < HH; ++j) {
            float y = __fmaf_rn(r[j], ahn[j], ain[j]);
            float u = fminf((2.0f * L2E) * y, 24.0f);
            dn[j] = exp2_hw(u) + 1.0f;
        }
        float idn[HH];
        inv5(dn, idn);

        #pragma unroll
        for (int j = 0; j < HH; ++j) {
            float nv = __fmaf_rn(-2.0f, idn[j], 1.0f);   // tanh
            // (1-z)*nv + z*h = z*(h - nv) + nv
            h[j] = __fmaf_rn(z[j], h[j] - nv, nv);
        }
    }

    // y = fc(h); out[(b*O + o)*S + s]
    float* op = out + (size_t)b * (OO * SS) + s;
    #pragma unroll
    for (int o = 0; o < OO; ++o) {
        float y = fc_b[o];
        #pragma unroll
        for (int k = 0; k < HH; ++k) y = __fmaf_rn(fc_w[o * HH + k], h[k], y);
        op[o * SS] = y;
    }
}

extern "C" void kernel_launch(void* const* d_in, const int* in_sizes, int n_in,
                              void* d_out, int out_size, void* d_ws, size_t ws_size,
                              hipStream_t stream) {
    const float* x    = (const float*)d_in[0];
    const float* w_ih = (const float*)d_in[1];
    const float* w_hh = (const float*)d_in[2];
    const float* b_ih = (const float*)d_in[3];
    const float* b_hh = (const float*)d_in[4];
    const float* fc_w = (const float*)d_in[5];
    const float* fc_b = (const float*)d_in[6];
    float* out = (float*)d_out;

    const int N = BB * SS;                 // 1,232,896
    const int block = 256;
    const int grid = (N + block - 1) / block;  // 4816 exactly
    gru_kernel<<<grid, block, 0, stream>>>(x, w_ih, w_hh, b_ih, b_hh, fc_w, fc_b, out);
}